// Round 2
// baseline (393.178 us; speedup 1.0000x reference)
//
#include <hip/hip_runtime.h>

typedef unsigned short u16;
typedef unsigned int   u32;

typedef short short8 __attribute__((ext_vector_type(8)));
typedef float floatx4 __attribute__((ext_vector_type(4)));

#define CDIM 128

__device__ __forceinline__ float bf2f(u32 h) {
    union { u32 u; float f; } v; v.u = h << 16; return v.f;
}
__device__ __forceinline__ u16 f2bf(float f) {
    union { float f; u32 u; } v; v.f = f;
    u32 u = v.u;
    return (u16)((u + 0x7FFFu + ((u >> 16) & 1u)) >> 16);  // RNE
}
__device__ __forceinline__ float sigmoidf_(float x) {
    return 1.0f / (1.0f + __expf(-x));
}

// fp32 -> bf16 elementwise (used once for the two 128x128 weight matrices)
__global__ __launch_bounds__(256) void cvt_kernel(
    const float* __restrict__ src, u16* __restrict__ dst, int n)
{
    int i = blockIdx.x * blockDim.x + threadIdx.x;
    if (i < n) dst[i] = f2bf(src[i]);
}

// out[r][c] = sum_k X[r][k] * W[c][k]  (+ bias[c]), X fp32, W pre-cvt bf16,
// out stored bf16. One wave per 16-row tile; K=128 via 4 MFMA steps.
__global__ __launch_bounds__(256) void proj_kernel(
    const float* __restrict__ X, const u16* __restrict__ Wbf,
    const float* __restrict__ bias, u16* __restrict__ out, int nrows)
{
    const int wave = threadIdx.x >> 6;
    const int lane = threadIdx.x & 63;
    const int rowTile = blockIdx.x * 4 + wave;
    const int row0 = rowTile * 16;
    if (row0 >= nrows) return;

    const int m = lane & 15;   // A-row / B-col / D-col
    const int g = lane >> 4;   // k-quad

    int arow = row0 + m;
    if (arow >= nrows) arow = nrows - 1;       // clamp; stores masked below
    const float* xrow = X + (size_t)arow * CDIM;

    short8 a[4];
#pragma unroll
    for (int s = 0; s < 4; ++s) {
        float4 f0 = *(const float4*)(xrow + s * 32 + g * 8);
        float4 f1 = *(const float4*)(xrow + s * 32 + g * 8 + 4);
        a[s][0] = (short)f2bf(f0.x); a[s][1] = (short)f2bf(f0.y);
        a[s][2] = (short)f2bf(f0.z); a[s][3] = (short)f2bf(f0.w);
        a[s][4] = (short)f2bf(f1.x); a[s][5] = (short)f2bf(f1.y);
        a[s][6] = (short)f2bf(f1.z); a[s][7] = (short)f2bf(f1.w);
    }

#pragma unroll
    for (int ct = 0; ct < 8; ++ct) {
        const u16* wrow = Wbf + (size_t)(ct * 16 + m) * CDIM;
        floatx4 acc = {0.f, 0.f, 0.f, 0.f};
#pragma unroll
        for (int s = 0; s < 4; ++s) {
            short8 b = *(const short8*)(wrow + s * 32 + g * 8);
            acc = __builtin_amdgcn_mfma_f32_16x16x32_bf16(a[s], b, acc, 0, 0, 0);
        }
        const int col = ct * 16 + m;           // D: col = lane&15
        const float badd = bias ? bias[col] : 0.f;
#pragma unroll
        for (int i = 0; i < 4; ++i) {
            int r = row0 + g * 4 + i;          // D: row = (lane>>4)*4 + reg
            if (r < nrows)
                out[(size_t)r * CDIM + col] = f2bf(acc[i] + badd);
        }
    }
}

// One wave per edge; lane handles channels 2*lane, 2*lane+1 (bf16 pairs).
__global__ __launch_bounds__(256) void edge_kernel(
    const u16* __restrict__ stu_p, const u16* __restrict__ item_p,
    const u16* __restrict__ conc_s, const u16* __restrict__ conc_i,
    const int* __restrict__ stu_track, const int* __restrict__ item_index,
    const int* __restrict__ conc_index, const int* __restrict__ mean_index,
    const float* __restrict__ w_pred,
    float* __restrict__ sums, float* __restrict__ cnts, int E)
{
    const int lane = threadIdx.x & 63;
    const int waveId = (int)((blockIdx.x * blockDim.x + threadIdx.x) >> 6);
    const int nWaves = (int)((gridDim.x * blockDim.x) >> 6);

    const float2 wv = ((const float2*)w_pred)[lane];
    const float w0 = wv.x, w1 = wv.y;

    for (int e = waveId; e < E; e += nWaves) {
        const int si = stu_track[e];
        const int ii = item_index[e];
        const int ci = conc_index[e];
        const int mi = mean_index[e];

        const u32 s2 = ((const u32*)stu_p )[(size_t)si * 64 + lane];
        const u32 i2 = ((const u32*)item_p)[(size_t)ii * 64 + lane];
        const u32 c2 = ((const u32*)conc_s)[(size_t)ci * 64 + lane];
        const u32 d2 = ((const u32*)conc_i)[(size_t)ci * 64 + lane];

        const float a0 = bf2f(c2 & 0xffffu) + bf2f(s2 & 0xffffu);
        const float a1 = bf2f(c2 >> 16)     + bf2f(s2 >> 16);
        const float b0 = bf2f(d2 & 0xffffu) + bf2f(i2 & 0xffffu);
        const float b1 = bf2f(d2 >> 16)     + bf2f(i2 >> 16);

        float v = w0 * (sigmoidf_(a0) - sigmoidf_(b0))
                + w1 * (sigmoidf_(a1) - sigmoidf_(b1));

#pragma unroll
        for (int off = 32; off > 0; off >>= 1)
            v += __shfl_down(v, off, 64);

        if (lane == 0) {
            atomicAdd(&sums[mi], v);
            atomicAdd(&cnts[mi], 1.0f);
        }
    }
}

__global__ __launch_bounds__(256) void final_kernel(
    const float* __restrict__ sums, const float* __restrict__ cnts,
    const float* __restrict__ b_pred, float* __restrict__ out, int M)
{
    const int i = blockIdx.x * blockDim.x + threadIdx.x;
    if (i < M) {
        const float mean = sums[i] / fmaxf(cnts[i], 1.0f);
        out[i] = sigmoidf_(mean + b_pred[0]);
    }
}

extern "C" void kernel_launch(void* const* d_in, const int* in_sizes, int n_in,
                              void* d_out, int out_size, void* d_ws, size_t ws_size,
                              hipStream_t stream) {
    const float* stu_x    = (const float*)d_in[0];
    const float* item_x   = (const float*)d_in[1];
    const float* conc_x   = (const float*)d_in[2];
    const float* W_stu    = (const float*)d_in[3];
    const float* b_stu    = (const float*)d_in[4];
    const float* W_item   = (const float*)d_in[5];
    const float* b_item   = (const float*)d_in[6];
    const float* W_pred   = (const float*)d_in[7];
    const float* b_pred   = (const float*)d_in[8];
    const int* stu_track  = (const int*)d_in[9];
    const int* item_index = (const int*)d_in[10];
    const int* conc_index = (const int*)d_in[11];
    const int* mean_index = (const int*)d_in[12];

    const int NS = in_sizes[0] / CDIM;
    const int NI = in_sizes[1] / CDIM;
    const int NC = in_sizes[2] / CDIM;
    const int E  = in_sizes[9];
    const int M  = out_size;

    // workspace layout (16B-aligned pieces)
    float* sums   = (float*)d_ws;
    float* cnts   = sums + M;
    u16*  Wstu_bf  = (u16*)(cnts + M);
    u16*  Witem_bf = Wstu_bf + CDIM * CDIM;
    u16*  stu_p    = Witem_bf + CDIM * CDIM;
    u16*  item_p   = stu_p  + (size_t)NS * CDIM;
    u16*  conc_s   = item_p + (size_t)NI * CDIM;
    u16*  conc_i   = conc_s + (size_t)NC * CDIM;

    hipMemsetAsync(sums, 0, (size_t)2 * M * sizeof(float), stream);

    cvt_kernel<<<(CDIM * CDIM + 255) / 256, 256, 0, stream>>>(W_stu,  Wstu_bf,  CDIM * CDIM);
    cvt_kernel<<<(CDIM * CDIM + 255) / 256, 256, 0, stream>>>(W_item, Witem_bf, CDIM * CDIM);

    proj_kernel<<<(NS + 63) / 64, 256, 0, stream>>>(stu_x,  Wstu_bf,  nullptr, stu_p,  NS);
    proj_kernel<<<(NI + 63) / 64, 256, 0, stream>>>(item_x, Witem_bf, nullptr, item_p, NI);
    proj_kernel<<<(NC + 63) / 64, 256, 0, stream>>>(conc_x, Wstu_bf,  b_stu,   conc_s, NC);
    proj_kernel<<<(NC + 63) / 64, 256, 0, stream>>>(conc_x, Witem_bf, b_item,  conc_i, NC);

    edge_kernel<<<4096, 256, 0, stream>>>(stu_p, item_p, conc_s, conc_i,
                                          stu_track, item_index, conc_index, mean_index,
                                          W_pred, sums, cnts, E);

    final_kernel<<<(M + 255) / 256, 256, 0, stream>>>(sums, cnts, b_pred, (float*)d_out, M);
}

// Round 3
// 240.258 us; speedup vs baseline: 1.6365x; 1.6365x over previous
//
#include <hip/hip_runtime.h>

typedef unsigned short u16;
typedef unsigned int   u32;

typedef short short8 __attribute__((ext_vector_type(8)));
typedef float floatx4 __attribute__((ext_vector_type(4)));

#define CDIM 128

__device__ __forceinline__ float bf2f_lo(u32 h) {
    union { u32 u; float f; } v; v.u = h << 16; return v.f;
}
__device__ __forceinline__ float bf2f_hi(u32 h) {
    union { u32 u; float f; } v; v.u = h & 0xffff0000u; return v.f;
}
__device__ __forceinline__ u16 f2bf(float f) {
    union { float f; u32 u; } v; v.f = f;
    u32 u = v.u;
    return (u16)((u + 0x7FFFu + ((u >> 16) & 1u)) >> 16);  // RNE
}
// fast sigmoid: v_exp + v_rcp (1 ulp each) instead of IEEE div expansion
__device__ __forceinline__ float sig(float x) {
    return __builtin_amdgcn_rcpf(1.0f + __expf(-x));
}

// fp32 -> bf16 for both weight matrices in one launch (dst = Wstu_bf || Witem_bf)
__global__ __launch_bounds__(256) void cvt2_kernel(
    const float* __restrict__ Wstu, const float* __restrict__ Witem,
    u16* __restrict__ dst)
{
    int i = blockIdx.x * blockDim.x + threadIdx.x;
    int n = CDIM * CDIM;
    if (i < 2 * n)
        dst[i] = f2bf(i < n ? Wstu[i] : Witem[i - n]);
}

// One wave computes a 32-row tile of out[r][c] = sum_k X[r][k]*W[c][k] (+bias[c]).
// Two 16-row A-tiles share each B fragment (halves W reload traffic).
__device__ __forceinline__ void proj_tile32(
    const float* __restrict__ X, const u16* __restrict__ Wbf,
    const float* __restrict__ bias, u16* __restrict__ out,
    int nrows, int ostride, int ooff, int row0, int lane)
{
    const int m = lane & 15;   // A-row / B-col / D-col
    const int g = lane >> 4;   // k-quad

    short8 a[2][4];
#pragma unroll
    for (int t = 0; t < 2; ++t) {
        int arow = row0 + t * 16 + m;
        if (arow >= nrows) arow = nrows - 1;   // clamp; stores masked below
        const float* xrow = X + (size_t)arow * CDIM;
#pragma unroll
        for (int s = 0; s < 4; ++s) {
            float4 f0 = *(const float4*)(xrow + s * 32 + g * 8);
            float4 f1 = *(const float4*)(xrow + s * 32 + g * 8 + 4);
            a[t][s][0] = (short)f2bf(f0.x); a[t][s][1] = (short)f2bf(f0.y);
            a[t][s][2] = (short)f2bf(f0.z); a[t][s][3] = (short)f2bf(f0.w);
            a[t][s][4] = (short)f2bf(f1.x); a[t][s][5] = (short)f2bf(f1.y);
            a[t][s][6] = (short)f2bf(f1.z); a[t][s][7] = (short)f2bf(f1.w);
        }
    }

#pragma unroll
    for (int ct = 0; ct < 8; ++ct) {
        const u16* wrow = Wbf + (size_t)(ct * 16 + m) * CDIM;
        floatx4 acc0 = {0.f, 0.f, 0.f, 0.f};
        floatx4 acc1 = {0.f, 0.f, 0.f, 0.f};
#pragma unroll
        for (int s = 0; s < 4; ++s) {
            short8 b = *(const short8*)(wrow + s * 32 + g * 8);
            acc0 = __builtin_amdgcn_mfma_f32_16x16x32_bf16(a[0][s], b, acc0, 0, 0, 0);
            acc1 = __builtin_amdgcn_mfma_f32_16x16x32_bf16(a[1][s], b, acc1, 0, 0, 0);
        }
        const int col = ct * 16 + m;           // D: col = lane&15
        const float badd = bias ? bias[col] : 0.f;
#pragma unroll
        for (int i = 0; i < 4; ++i) {
            int r0 = row0 + g * 4 + i;         // D: row = (lane>>4)*4 + reg
            if (r0 < nrows)
                out[(size_t)r0 * ostride + ooff + col] = f2bf(acc0[i] + badd);
            int r1 = r0 + 16;
            if (r1 < nrows)
                out[(size_t)r1 * ostride + ooff + col] = f2bf(acc1[i] + badd);
        }
    }
}

// All four projections in one launch; wave-uniform segment select.
__global__ __launch_bounds__(256) void proj4_kernel(
    const float* __restrict__ stu_x, const float* __restrict__ item_x,
    const float* __restrict__ conc_x,
    const u16* __restrict__ Wstu_bf, const u16* __restrict__ Witem_bf,
    const float* __restrict__ b_stu, const float* __restrict__ b_item,
    u16* __restrict__ stu_p, u16* __restrict__ item_p, u16* __restrict__ conc_cat,
    int NS, int NI, int NC)
{
    const int lane = threadIdx.x & 63;
    int w = blockIdx.x * 4 + (threadIdx.x >> 6);
    const int T0 = (NS + 31) / 32, T1 = (NI + 31) / 32, T2 = (NC + 31) / 32;

    if (w < T0) { proj_tile32(stu_x, Wstu_bf, nullptr, stu_p, NS, 128, 0, w * 32, lane); return; }
    w -= T0;
    if (w < T1) { proj_tile32(item_x, Witem_bf, nullptr, item_p, NI, 128, 0, w * 32, lane); return; }
    w -= T1;
    if (w < T2) { proj_tile32(conc_x, Wstu_bf, b_stu, conc_cat, NC, 256, 0, w * 32, lane); return; }
    w -= T2;
    if (w < T2) { proj_tile32(conc_x, Witem_bf, b_item, conc_cat, NC, 256, 128, w * 32, lane); return; }
}

// 16 lanes per edge, 4 edges per wave. Lane handles channels sub*8..sub*8+7.
__global__ __launch_bounds__(256) void edge_kernel(
    const u16* __restrict__ stu_p, const u16* __restrict__ item_p,
    const u16* __restrict__ conc_cat,
    const int* __restrict__ stu_track, const int* __restrict__ item_index,
    const int* __restrict__ conc_index, const int* __restrict__ mean_index,
    const float* __restrict__ w_pred,
    float* __restrict__ sums, float* __restrict__ cnts, int E)
{
    const int lane = threadIdx.x & 63;
    const int sub  = lane & 15;      // position within edge
    const int g    = lane >> 4;      // edge within quad
    const int waveId = (int)((blockIdx.x * blockDim.x + threadIdx.x) >> 6);
    const int nWaves = (int)((gridDim.x * blockDim.x) >> 6);

    // 8 w_pred weights for this lane's channels (shared by all 4 edges)
    const float4 wA = ((const float4*)w_pred)[sub * 2];
    const float4 wB = ((const float4*)w_pred)[sub * 2 + 1];
    const float w8[8] = {wA.x, wA.y, wA.z, wA.w, wB.x, wB.y, wB.z, wB.w};

    const int nQuads = (E + 3) >> 2;
    for (int q = waveId; q < nQuads; q += nWaves) {
        const int e = q * 4 + g;
        float v = 0.f;
        int mi = 0;
        bool live = (e < E);
        if (live) {
            const int si = stu_track[e];
            const int ii = item_index[e];
            const int ci = conc_index[e];
            mi = mean_index[e];

            // 32-bit byte offsets -> saddr + voffset addressing
            const u32 soff = ((u32)si << 8) + (u32)sub * 16;   // 256 B rows
            const u32 ioff = ((u32)ii << 8) + (u32)sub * 16;
            const u32 coff = ((u32)ci << 9) + (u32)sub * 16;   // 512 B rows (cat)

            const uint4 sv = *(const uint4*)((const char*)stu_p  + soff);
            const uint4 iv = *(const uint4*)((const char*)item_p + ioff);
            const uint4 ca = *(const uint4*)((const char*)conc_cat + coff);
            const uint4 cb = *(const uint4*)((const char*)conc_cat + coff + 256);

            const u32 su[4] = {sv.x, sv.y, sv.z, sv.w};
            const u32 iu[4] = {iv.x, iv.y, iv.z, iv.w};
            const u32 au[4] = {ca.x, ca.y, ca.z, ca.w};
            const u32 bu[4] = {cb.x, cb.y, cb.z, cb.w};

#pragma unroll
            for (int j = 0; j < 4; ++j) {
                const float a0 = bf2f_lo(au[j]) + bf2f_lo(su[j]);
                const float a1 = bf2f_hi(au[j]) + bf2f_hi(su[j]);
                const float b0 = bf2f_lo(bu[j]) + bf2f_lo(iu[j]);
                const float b1 = bf2f_hi(bu[j]) + bf2f_hi(iu[j]);
                v += w8[2 * j]     * (sig(a0) - sig(b0));
                v += w8[2 * j + 1] * (sig(a1) - sig(b1));
            }
        }

        // reduce within each 16-lane group (masks < 16 stay in-group)
        v += __shfl_xor(v, 1, 64);
        v += __shfl_xor(v, 2, 64);
        v += __shfl_xor(v, 4, 64);
        v += __shfl_xor(v, 8, 64);

        if (sub == 0 && live) {
            atomicAdd(&sums[mi], v);
            atomicAdd(&cnts[mi], 1.0f);
        }
    }
}

__global__ __launch_bounds__(256) void final_kernel(
    const float* __restrict__ sums, const float* __restrict__ cnts,
    const float* __restrict__ b_pred, float* __restrict__ out, int M)
{
    const int i = blockIdx.x * blockDim.x + threadIdx.x;
    if (i < M) {
        const float mean = sums[i] / fmaxf(cnts[i], 1.0f);
        out[i] = sig(mean + b_pred[0]);
    }
}

extern "C" void kernel_launch(void* const* d_in, const int* in_sizes, int n_in,
                              void* d_out, int out_size, void* d_ws, size_t ws_size,
                              hipStream_t stream) {
    const float* stu_x    = (const float*)d_in[0];
    const float* item_x   = (const float*)d_in[1];
    const float* conc_x   = (const float*)d_in[2];
    const float* W_stu    = (const float*)d_in[3];
    const float* b_stu    = (const float*)d_in[4];
    const float* W_item   = (const float*)d_in[5];
    const float* b_item   = (const float*)d_in[6];
    const float* W_pred   = (const float*)d_in[7];
    const float* b_pred   = (const float*)d_in[8];
    const int* stu_track  = (const int*)d_in[9];
    const int* item_index = (const int*)d_in[10];
    const int* conc_index = (const int*)d_in[11];
    const int* mean_index = (const int*)d_in[12];

    const int NS = in_sizes[0] / CDIM;
    const int NI = in_sizes[1] / CDIM;
    const int NC = in_sizes[2] / CDIM;
    const int E  = in_sizes[9];
    const int M  = out_size;

    // workspace layout (all pieces 16B-aligned)
    float* sums    = (float*)d_ws;
    float* cnts    = sums + M;
    u16* Wstu_bf   = (u16*)(cnts + M);           // Wstu_bf || Witem_bf contiguous
    u16* Witem_bf  = Wstu_bf + CDIM * CDIM;
    u16* stu_p     = Witem_bf + CDIM * CDIM;
    u16* item_p    = stu_p  + (size_t)NS * CDIM;
    u16* conc_cat  = item_p + (size_t)NI * CDIM; // [NC][256]: conc_s | conc_i

    hipMemsetAsync(sums, 0, (size_t)2 * M * sizeof(float), stream);

    cvt2_kernel<<<(2 * CDIM * CDIM + 255) / 256, 256, 0, stream>>>(W_stu, W_item, Wstu_bf);

    const int T0 = (NS + 31) / 32, T1 = (NI + 31) / 32, T2 = (NC + 31) / 32;
    const int totalWaves = T0 + T1 + 2 * T2;
    proj4_kernel<<<(totalWaves + 3) / 4, 256, 0, stream>>>(
        stu_x, item_x, conc_x, Wstu_bf, Witem_bf, b_stu, b_item,
        stu_p, item_p, conc_cat, NS, NI, NC);

    edge_kernel<<<4096, 256, 0, stream>>>(stu_p, item_p, conc_cat,
                                          stu_track, item_index, conc_index, mean_index,
                                          W_pred, sums, cnts, E);

    final_kernel<<<(M + 255) / 256, 256, 0, stream>>>(sums, cnts, b_pred, (float*)d_out, M);
}

// Round 4
// 233.489 us; speedup vs baseline: 1.6839x; 1.0290x over previous
//
#include <hip/hip_runtime.h>

typedef unsigned short u16;
typedef unsigned int   u32;

typedef short short8 __attribute__((ext_vector_type(8)));
typedef float floatx4 __attribute__((ext_vector_type(4)));

#define CDIM 128
#define K_NEG_LOG2E -1.4426950408889634f

__device__ __forceinline__ float bf2f_lo(u32 h) {
    union { u32 u; float f; } v; v.u = h << 16; return v.f;
}
__device__ __forceinline__ float bf2f_hi(u32 h) {
    union { u32 u; float f; } v; v.u = h & 0xffff0000u; return v.f;
}
__device__ __forceinline__ u16 f2bf(float f) {
    union { float f; u32 u; } v; v.f = f;
    u32 u = v.u;
    return (u16)((u + 0x7FFFu + ((u >> 16) & 1u)) >> 16);  // RNE
}
// sigmoid on PRE-SCALED argument y = -log2(e) * x:  sigma(x) = rcp(1 + 2^y)
__device__ __forceinline__ float sig_pre(float y) {
    return __builtin_amdgcn_rcpf(1.0f + __builtin_amdgcn_exp2f(y));
}
// standard sigmoid (final kernel only)
__device__ __forceinline__ float sig_std(float x) {
    return __builtin_amdgcn_rcpf(1.0f + __builtin_amdgcn_exp2f(x * K_NEG_LOG2E));
}

// One launch: zero sums/cnts AND convert both weight matrices to bf16
// pre-scaled by -log2(e) (so the edge kernel's sigmoid needs no multiply).
__global__ __launch_bounds__(256) void prep_kernel(
    const float* __restrict__ Wstu, const float* __restrict__ Witem,
    u32* __restrict__ Wbf_pair, float4* __restrict__ zero4, int nZero4)
{
    const int tid = blockIdx.x * blockDim.x + threadIdx.x;
    const int stride = gridDim.x * blockDim.x;
    // 2 * 128*128 floats = 16384 u32 pairs (first 8192 = Wstu, rest = Witem)
    for (int i = tid; i < 16384; i += stride) {
        const float* W = (i & 8192) ? (Witem - 16384) : Wstu;  // adjust base
        const int j = i * 2;
        u32 lo = f2bf(W[j]     * K_NEG_LOG2E);
        u32 hi = f2bf(W[j + 1] * K_NEG_LOG2E);
        Wbf_pair[i] = lo | (hi << 16);
    }
    const float4 z = {0.f, 0.f, 0.f, 0.f};
    for (int i = tid; i < nZero4; i += stride) zero4[i] = z;
}

// One wave computes a 32-row tile of out[r][c] = sum_k X[r][k]*W[c][k] (+bias[c]).
// W pre-scaled bf16; bias scaled here. Output bf16 (pre-scaled domain).
__device__ __forceinline__ void proj_tile32(
    const float* __restrict__ X, const u16* __restrict__ Wbf,
    const float* __restrict__ bias, u16* __restrict__ out,
    int nrows, int ostride, int ooff, int row0, int lane)
{
    const int m = lane & 15;   // A-row / B-col / D-col
    const int g = lane >> 4;   // k-quad

    short8 a[2][4];
#pragma unroll
    for (int t = 0; t < 2; ++t) {
        int arow = row0 + t * 16 + m;
        if (arow >= nrows) arow = nrows - 1;   // clamp; stores masked below
        const float* xrow = X + (size_t)arow * CDIM;
#pragma unroll
        for (int s = 0; s < 4; ++s) {
            float4 f0 = *(const float4*)(xrow + s * 32 + g * 8);
            float4 f1 = *(const float4*)(xrow + s * 32 + g * 8 + 4);
            a[t][s][0] = (short)f2bf(f0.x); a[t][s][1] = (short)f2bf(f0.y);
            a[t][s][2] = (short)f2bf(f0.z); a[t][s][3] = (short)f2bf(f0.w);
            a[t][s][4] = (short)f2bf(f1.x); a[t][s][5] = (short)f2bf(f1.y);
            a[t][s][6] = (short)f2bf(f1.z); a[t][s][7] = (short)f2bf(f1.w);
        }
    }

#pragma unroll
    for (int ct = 0; ct < 8; ++ct) {
        const u16* wrow = Wbf + (size_t)(ct * 16 + m) * CDIM;
        floatx4 acc0 = {0.f, 0.f, 0.f, 0.f};
        floatx4 acc1 = {0.f, 0.f, 0.f, 0.f};
#pragma unroll
        for (int s = 0; s < 4; ++s) {
            short8 b = *(const short8*)(wrow + s * 32 + g * 8);
            acc0 = __builtin_amdgcn_mfma_f32_16x16x32_bf16(a[0][s], b, acc0, 0, 0, 0);
            acc1 = __builtin_amdgcn_mfma_f32_16x16x32_bf16(a[1][s], b, acc1, 0, 0, 0);
        }
        const int col = ct * 16 + m;           // D: col = lane&15
        const float badd = bias ? bias[col] * K_NEG_LOG2E : 0.f;
#pragma unroll
        for (int i = 0; i < 4; ++i) {
            int r0 = row0 + g * 4 + i;         // D: row = (lane>>4)*4 + reg
            if (r0 < nrows)
                out[(size_t)r0 * ostride + ooff + col] = f2bf(acc0[i] + badd);
            int r1 = r0 + 16;
            if (r1 < nrows)
                out[(size_t)r1 * ostride + ooff + col] = f2bf(acc1[i] + badd);
        }
    }
}

// All four projections in one launch; wave-uniform segment select.
__global__ __launch_bounds__(256) void proj4_kernel(
    const float* __restrict__ stu_x, const float* __restrict__ item_x,
    const float* __restrict__ conc_x,
    const u16* __restrict__ Wstu_bf, const u16* __restrict__ Witem_bf,
    const float* __restrict__ b_stu, const float* __restrict__ b_item,
    u16* __restrict__ stu_p, u16* __restrict__ item_p, u16* __restrict__ conc_cat,
    int NS, int NI, int NC)
{
    const int lane = threadIdx.x & 63;
    int w = blockIdx.x * 4 + (threadIdx.x >> 6);
    const int T0 = (NS + 31) / 32, T1 = (NI + 31) / 32, T2 = (NC + 31) / 32;

    if (w < T0) { proj_tile32(stu_x, Wstu_bf, nullptr, stu_p, NS, 128, 0, w * 32, lane); return; }
    w -= T0;
    if (w < T1) { proj_tile32(item_x, Witem_bf, nullptr, item_p, NI, 128, 0, w * 32, lane); return; }
    w -= T1;
    if (w < T2) { proj_tile32(conc_x, Wstu_bf, b_stu, conc_cat, NC, 256, 0, w * 32, lane); return; }
    w -= T2;
    if (w < T2) { proj_tile32(conc_x, Witem_bf, b_item, conc_cat, NC, 256, 128, w * 32, lane); return; }
}

// 16 lanes per edge, 4 edges per wave; next-iteration indices prefetched.
__global__ __launch_bounds__(256) void edge_kernel(
    const u16* __restrict__ stu_p, const u16* __restrict__ item_p,
    const u16* __restrict__ conc_cat,
    const int* __restrict__ stu_track, const int* __restrict__ item_index,
    const int* __restrict__ conc_index, const int* __restrict__ mean_index,
    const float* __restrict__ w_pred,
    float* __restrict__ sums, float* __restrict__ cnts, int E)
{
    const int lane = threadIdx.x & 63;
    const int sub  = lane & 15;      // position within edge
    const int g    = lane >> 4;      // edge within quad
    const int waveId = (int)((blockIdx.x * blockDim.x + threadIdx.x) >> 6);
    const int nWaves = (int)((gridDim.x * blockDim.x) >> 6);

    // 8 w_pred weights for this lane's channels (shared by all 4 edges)
    const float4 wA = ((const float4*)w_pred)[sub * 2];
    const float4 wB = ((const float4*)w_pred)[sub * 2 + 1];
    const float w8[8] = {wA.x, wA.y, wA.z, wA.w, wB.x, wB.y, wB.z, wB.w};
    const u32 lane_off = (u32)sub * 16;

    const int nQuads = (E + 3) >> 2;
    int q = waveId;
    if (q >= nQuads) return;

    int e = q * 4 + g;
    int ec = (e < E) ? e : (E - 1);
    int si = stu_track[ec], ii = item_index[ec], ci = conc_index[ec], mi = mean_index[ec];
    bool live = (e < E);

    while (true) {
        // gathers for the current quad (indices already in registers)
        const uint4 sv = *(const uint4*)((const char*)stu_p  + (((u32)si << 8) + lane_off));
        const uint4 iv = *(const uint4*)((const char*)item_p + (((u32)ii << 8) + lane_off));
        const char* cbase = (const char*)conc_cat + (((u32)ci << 9) + lane_off);
        const uint4 ca = *(const uint4*)cbase;
        const uint4 cb = *(const uint4*)(cbase + 256);

        // prefetch next iteration's indices (overlaps with compute below)
        const int qn = q + nWaves;
        const bool more = (qn < nQuads);
        int si2, ii2, ci2, mi2; bool live2 = false;
        if (more) {
            int e2 = qn * 4 + g;
            int ec2 = (e2 < E) ? e2 : (E - 1);
            si2 = stu_track[ec2]; ii2 = item_index[ec2];
            ci2 = conc_index[ec2]; mi2 = mean_index[ec2];
            live2 = (e2 < E);
        }

        const u32 su[4] = {sv.x, sv.y, sv.z, sv.w};
        const u32 iu[4] = {iv.x, iv.y, iv.z, iv.w};
        const u32 au[4] = {ca.x, ca.y, ca.z, ca.w};
        const u32 bu[4] = {cb.x, cb.y, cb.z, cb.w};

        float v = 0.f;
#pragma unroll
        for (int j = 0; j < 4; ++j) {
            const float a0 = bf2f_lo(au[j]) + bf2f_lo(su[j]);
            const float a1 = bf2f_hi(au[j]) + bf2f_hi(su[j]);
            const float b0 = bf2f_lo(bu[j]) + bf2f_lo(iu[j]);
            const float b1 = bf2f_hi(bu[j]) + bf2f_hi(iu[j]);
            v += w8[2 * j]     * (sig_pre(a0) - sig_pre(b0));
            v += w8[2 * j + 1] * (sig_pre(a1) - sig_pre(b1));
        }

        // reduce within each 16-lane group (masks < 16 stay in-group)
        v += __shfl_xor(v, 1, 64);
        v += __shfl_xor(v, 2, 64);
        v += __shfl_xor(v, 4, 64);
        v += __shfl_xor(v, 8, 64);

        if (sub == 0 && live) {
            atomicAdd(&sums[mi], v);
            atomicAdd(&cnts[mi], 1.0f);
        }

        if (!more) break;
        q = qn; si = si2; ii = ii2; ci = ci2; mi = mi2; live = live2;
    }
}

__global__ __launch_bounds__(256) void final_kernel(
    const float* __restrict__ sums, const float* __restrict__ cnts,
    const float* __restrict__ b_pred, float* __restrict__ out, int M)
{
    const int i = blockIdx.x * blockDim.x + threadIdx.x;
    if (i < M) {
        const float mean = sums[i] / fmaxf(cnts[i], 1.0f);
        out[i] = sig_std(mean + b_pred[0]);
    }
}

extern "C" void kernel_launch(void* const* d_in, const int* in_sizes, int n_in,
                              void* d_out, int out_size, void* d_ws, size_t ws_size,
                              hipStream_t stream) {
    const float* stu_x    = (const float*)d_in[0];
    const float* item_x   = (const float*)d_in[1];
    const float* conc_x   = (const float*)d_in[2];
    const float* W_stu    = (const float*)d_in[3];
    const float* b_stu    = (const float*)d_in[4];
    const float* W_item   = (const float*)d_in[5];
    const float* b_item   = (const float*)d_in[6];
    const float* W_pred   = (const float*)d_in[7];
    const float* b_pred   = (const float*)d_in[8];
    const int* stu_track  = (const int*)d_in[9];
    const int* item_index = (const int*)d_in[10];
    const int* conc_index = (const int*)d_in[11];
    const int* mean_index = (const int*)d_in[12];

    const int NS = in_sizes[0] / CDIM;
    const int NI = in_sizes[1] / CDIM;
    const int NC = in_sizes[2] / CDIM;
    const int E  = in_sizes[9];
    const int M  = out_size;

    // workspace layout (all pieces 16B-aligned)
    float* sums    = (float*)d_ws;
    float* cnts    = sums + M;
    u16* Wstu_bf   = (u16*)(cnts + M);           // Wstu_bf || Witem_bf contiguous
    u16* Witem_bf  = Wstu_bf + CDIM * CDIM;
    u16* stu_p     = Witem_bf + CDIM * CDIM;
    u16* item_p    = stu_p  + (size_t)NS * CDIM;
    u16* conc_cat  = item_p + (size_t)NI * CDIM; // [NC][256]: conc_s | conc_i

    const int nZero4 = (2 * M) / 4;              // sums+cnts as float4 (M % 2 == 0)
    prep_kernel<<<512, 256, 0, stream>>>(W_stu, W_item, (u32*)Wstu_bf,
                                         (float4*)sums, nZero4);

    const int T0 = (NS + 31) / 32, T1 = (NI + 31) / 32, T2 = (NC + 31) / 32;
    const int totalWaves = T0 + T1 + 2 * T2;
    proj4_kernel<<<(totalWaves + 3) / 4, 256, 0, stream>>>(
        stu_x, item_x, conc_x, Wstu_bf, Witem_bf, b_stu, b_item,
        stu_p, item_p, conc_cat, NS, NI, NC);

    edge_kernel<<<4096, 256, 0, stream>>>(stu_p, item_p, conc_cat,
                                          stu_track, item_index, conc_index, mean_index,
                                          W_pred, sums, cnts, E);

    final_kernel<<<(M + 255) / 256, 256, 0, stream>>>(sums, cnts, b_pred, (float*)d_out, M);
}